// Round 17
// baseline (748.773 us; speedup 1.0000x reference)
//
#include <hip/hip_runtime.h>
#include <hip/hip_bf16.h>
#include <cstdint>

// EdgeFrontierPolicy: E=400000, G=64, H=256.
// r7 wave-independent design (verified correct) with its two diseases fixed:
//  - NO LDS at all: W1 frags read from L2 like W2 (identical packed layout)
//    -> no prologue barrier, no 128KB/block residency limit
//  - launch_bounds(256,3): 170-reg budget (r9-r16 verified spill-free band)
// Each 64-lane wave owns a 32-edge tile end-to-end, ZERO barriers anywhere:
// resident waves drift into different phases -> HBM/matrix/VALU pipes overlap
// on every SIMD (the phase-lockstep that capped r9-r16 at ~53% issue is gone).
// Per wave: 2-pass LN -> zln B-frags (regs) -> G1 transposed (h1^T = W1g^T x
// zln, A-frags from L2) -> gelu -> pk-shuffle -> h1f -> G2 transposed
// (h2^T = W2^T x h1^T, A-frags from L2, reg-rotated) -> gelu -> logits+pooled.

typedef __bf16 bf16x8 __attribute__((ext_vector_type(8)));
typedef float  f32x4  __attribute__((ext_vector_type(4)));

__device__ __forceinline__ float gelu_f(float x) {
  float x2 = x * x;
  float t1 = __builtin_fmaf(0.1029444f, x2, 2.3022078f);
  float a  = x * t1;
  float e;
  asm("v_exp_f32 %0, %1" : "=v"(e) : "v"(a));
  float r;
  asm("v_rcp_f32 %0, %1" : "=v"(r) : "v"(e + 1.0f));
  return x - x * r;
}

__device__ __forceinline__ bf16x8 as_frag(uint4 u) {
  union { uint4 u; bf16x8 f; } c; c.u = u; return c.f;
}
__device__ __forceinline__ unsigned pk2(float a, float b) {
  union { __bf16 h[2]; unsigned u; } c;
  c.h[0] = (__bf16)a; c.h[1] = (__bf16)b; return c.u;
}

// ---------------------------------------------------------------------------
// Pack W1 (ln1_g folded) / W2 into MFMA frag order, bf16.
// out[((kt*16+nt)*64 + l)*8 + i] = W[32kt + 8*(l>>4)+i][16nt + (l&15)]
// (B-frag pack of W == A-frag pack of W^T: one layout serves both GEMMs.)
__global__ void prep_pack(const float* __restrict__ W1, const float* __restrict__ W2,
                          const float* __restrict__ ln1g,
                          __bf16* __restrict__ W1p, __bf16* __restrict__ W2p) {
  int gid = blockIdx.x * blockDim.x + threadIdx.x;   // 16384 threads
  int m  = gid >> 13;
  int b  = (gid >> 6) & 127;
  int l  = gid & 63;
  int kt = b >> 4, nt = b & 15;
  int k0 = kt * 32 + ((l >> 4) << 3);
  int n  = nt * 16 + (l & 15);
  const float* W = m ? W2 : W1;
  bf16x8 v;
#pragma unroll
  for (int i = 0; i < 8; ++i) {
    int k = k0 + i;
    float wv = W[k * 256 + n];
    if (!m) wv *= ln1g[k];
    v[i] = (__bf16)wv;
  }
  __bf16* dst = m ? W2p : W1p;
  *(bf16x8*)(dst + (size_t)(b * 64 + l) * 8) = v;
}

// C0/GW6/GW7 + mask dtype detect.
__global__ void prep_vec(const float* __restrict__ W1, const float* __restrict__ ln1g,
                         const float* __restrict__ ln1b, const float* __restrict__ b1,
                         const unsigned* __restrict__ smask_words,
                         float* __restrict__ C0, float* __restrict__ GW6,
                         float* __restrict__ GW7, int* __restrict__ maskIsByte) {
  __shared__ float red[4][256];
  const int n = threadIdx.x & 255, c = threadIdx.x >> 8;
  const int k0 = c * 64, k1 = (c == 3) ? 258 : k0 + 64;
  float s = 0.f;
#pragma unroll 4
  for (int k = k0; k < k1; ++k) s += ln1b[k] * W1[k * 256 + n];
  red[c][n] = s;
  __syncthreads();
  if (c == 0) {
    C0[n]  = b1[n] + red[0][n] + red[1][n] + red[2][n] + red[3][n];
    GW6[n] = ln1g[256] * W1[256 * 256 + n];
    GW7[n] = ln1g[257] * W1[257 * 256 + n];
  }
  if (threadIdx.x == 0) {
    int big = 0;
    for (int i = 0; i < 64; ++i) { if (smask_words[i] > 1u) big = 1; }
    *maskIsByte = big;
  }
}

// ---------------------------------------------------------------------------
__global__ __launch_bounds__(256, 3) void edge_kernel(
    const float* __restrict__ tok, const int* __restrict__ ebatch,
    const unsigned char* __restrict__ smaskB,
    const int* __restrict__ eheads, const int* __restrict__ etails,
    const int* __restrict__ curtail,
    const __bf16* __restrict__ W1p, const __bf16* __restrict__ W2p,
    const float* __restrict__ C0v, const float* __restrict__ GW6v,
    const float* __restrict__ GW7v, const float* __restrict__ b2v,
    const float* __restrict__ selwv, const float* __restrict__ selbv,
    const int* __restrict__ maskFlag,
    float* __restrict__ outLogits, float* __restrict__ pooledAcc,
    float* __restrict__ cnts) {
  const int t  = threadIdx.x;
  const int w  = t >> 6, l = t & 63;
  const int lo = l & 15, g = l >> 4;
  const int mb = *maskFlag;
  const float selbr = selbv[0];
  const char* W1c = (const char*)W1p;
  const char* W2c = (const char*)W2p;

  const int tile = blockIdx.x * 4 + w;     // each wave owns one 32-edge tile
  const int base = tile << 5;

  // ---- flags (lanes 0..31, one edge each) ----
  float candf = 0.f, frontf = 0.f; int gid = 0;
  if (l < 32) {
    int ge = base + l;
    gid = ebatch[ge];
    int mv = mb ? (int)smaskB[ge] : ((const int*)smaskB)[ge];
    int cand = (mv == 0);
    int cur  = curtail[gid];
    int fr   = cand && ((eheads[ge] == cur) || (etails[ge] == cur));
    candf = (float)cand; frontf = (float)fr;
  }
  const int g0s = __shfl(gid, 0);
  const bool uniform = (__ballot((l < 32) ? (gid == g0s) : 1) == ~0ull);
  {  // counts: boundary lanes add run lengths
    int gp = __shfl(gid, (l == 0) ? 0 : l - 1);
    bool isb = (l < 32) && (l == 0 || gid != gp);
    unsigned long long bm = __ballot(isb);
    if (isb) {
      unsigned long long m2 = bm >> (l + 1);
      int run = m2 ? (int)__ffsll((long long)m2) : (32 - l);
      atomicAdd(&cnts[gid], (float)run);
    }
  }
  // flags to row owners (edge a = lo, edge b = 16+lo)
  const float ca  = __shfl(candf, lo),      fa  = __shfl(frontf, lo);
  const float cb_ = __shfl(candf, 16 + lo), fb_ = __shfl(frontf, 16 + lo);
  const int   ga  = __shfl(gid, lo),        gb  = __shfl(gid, 16 + lo);

  uint4 h1f[2][8];   // h1 frags: A-frag of h1 == B-frag of h1^T

  // ==== per edge-half: 2-pass LN -> zln -> G1 -> gelu -> shuffle -> h1f ====
#pragma unroll
  for (int mt = 0; mt < 2; ++mt) {
    const float aux0 = mt ? cb_ : ca, aux1 = mt ? fb_ : fa;
    const float* rp = tok + (size_t)(base + mt * 16 + lo) * 256 + (g << 3);

    // pass 1: stats only (values discarded -> low pressure)
    float s = 0.f, s2 = 0.f;
#pragma unroll
    for (int kt = 0; kt < 8; ++kt) {
      float4 x0 = *(const float4*)(rp + kt * 32);
      float4 x1 = *(const float4*)(rp + kt * 32 + 4);
      s  += x0.x + x0.y + x0.z + x0.w + x1.x + x1.y + x1.z + x1.w;
      s2 += x0.x*x0.x + x0.y*x0.y + x0.z*x0.z + x0.w*x0.w
          + x1.x*x1.x + x1.y*x1.y + x1.z*x1.z + x1.w*x1.w;
    }
    s  += __shfl_xor(s, 16);  s  += __shfl_xor(s, 32);
    s2 += __shfl_xor(s2, 16); s2 += __shfl_xor(s2, 32);
    s += aux0 + aux1; s2 += aux0 + aux1;          // 0/1 flags: x == x^2
    const float mean = s * (1.0f / 258.0f);
    const float var  = s2 * (1.0f / 258.0f) - mean * mean;
    const float rstd = rsqrtf(var + 1e-5f);
    const float nm   = -mean * rstd;
    const float za0  = __builtin_fmaf(aux0, rstd, nm);
    const float za1  = __builtin_fmaf(aux1, rstd, nm);

    // pass 2: reload (L2-hot; opaque ptr defeats CSE with pass 1) + pack
    const float* rp2 = rp;
    asm volatile("" : "+v"(rp2));
    uint4 zln[8];
#pragma unroll
    for (int kt = 0; kt < 8; ++kt) {
      float4 x0 = *(const float4*)(rp2 + kt * 32);
      float4 x1 = *(const float4*)(rp2 + kt * 32 + 4);
      union { __bf16 h[8]; uint4 u; } cv;
      cv.h[0] = (__bf16)__builtin_fmaf(x0.x, rstd, nm);
      cv.h[1] = (__bf16)__builtin_fmaf(x0.y, rstd, nm);
      cv.h[2] = (__bf16)__builtin_fmaf(x0.z, rstd, nm);
      cv.h[3] = (__bf16)__builtin_fmaf(x0.w, rstd, nm);
      cv.h[4] = (__bf16)__builtin_fmaf(x1.x, rstd, nm);
      cv.h[5] = (__bf16)__builtin_fmaf(x1.y, rstd, nm);
      cv.h[6] = (__bf16)__builtin_fmaf(x1.z, rstd, nm);
      cv.h[7] = (__bf16)__builtin_fmaf(x1.w, rstd, nm);
      zln[kt] = cv.u;
    }

    // G1: h1^T[j][edge16] = W1g^T x zln, j-groups of 4 (A-frags from L2)
#pragma unroll
    for (int jg = 0; jg < 4; ++jg) {
      f32x4 acc[4];
#pragma unroll
      for (int jl = 0; jl < 4; ++jl) {
        const int j16 = (jg * 4 + jl) * 16 + g * 4;
        f32x4 c0 = *(const f32x4*)(C0v + j16);
        f32x4 w6 = *(const f32x4*)(GW6v + j16);
        f32x4 w7 = *(const f32x4*)(GW7v + j16);
#pragma unroll
        for (int i = 0; i < 4; ++i)
          acc[jl][i] = c0[i] + za0 * w6[i] + za1 * w7[i];
      }
#pragma unroll
      for (int kt = 0; kt < 8; ++kt) {
        bf16x8 bz = as_frag(zln[kt]);
#pragma unroll
        for (int jl = 0; jl < 4; ++jl) {
          bf16x8 afr = as_frag(*(const uint4*)(
              W1c + (size_t)((kt * 16 + jg * 4 + jl) * 1024) + l * 16));
          acc[jl] = __builtin_amdgcn_mfma_f32_16x16x32_bf16(afr, bz, acc[jl], 0, 0, 0);
        }
      }
      // gelu + pack
      unsigned pk[4][2];
#pragma unroll
      for (int jl = 0; jl < 4; ++jl) {
        pk[jl][0] = pk2(gelu_f(acc[jl][0]), gelu_f(acc[jl][1]));
        pk[jl][1] = pk2(gelu_f(acc[jl][2]), gelu_f(acc[jl][3]));
      }
      // shuffle h1^T -> h1 frags (r4-r7 verified mapping)
#pragma unroll
      for (int k2l = 0; k2l < 2; ++k2l) {
        unsigned dw[4];
#pragma unroll
        for (int tt = 0; tt < 4; ++tt) {
          int src = 16 * (2 * (g & 1) + (tt >> 1)) + lo;
          unsigned dE = __shfl(pk[2 * k2l][tt & 1], src);
          unsigned dO = __shfl(pk[2 * k2l + 1][tt & 1], src);
          dw[tt] = (g >= 2) ? dO : dE;
        }
        h1f[mt][jg * 2 + k2l] = make_uint4(dw[0], dw[1], dw[2], dw[3]);
      }
    }
  }  // mt

  asm volatile("" ::: "memory");   // fence: keep G2 loads out of G1's window

  // ==== G2^T: h2^T = W2^T x h1^T; A=W2p frag (L2), B=h1f (regs) ====
  float plog0 = 0.f, plog1 = 0.f;
#pragma unroll 4
  for (int cb = 0; cb < 16; ++cb) {
    f32x4 bb = *(const f32x4*)(b2v   + cb * 16 + g * 4);
    f32x4 sw = *(const f32x4*)(selwv + cb * 16 + g * 4);
    f32x4 a0 = bb, a1 = bb;
    const char* wb = W2c + (size_t)(cb * 1024) + l * 16;
    uint4 wf[4];
#pragma unroll
    for (int p = 0; p < 4; ++p) wf[p] = *(const uint4*)(wb + p * 16384);
#pragma unroll
    for (int kt2 = 0; kt2 < 8; ++kt2) {
      bf16x8 af = as_frag(wf[kt2 & 3]);
      if (kt2 < 4) wf[kt2 & 3] = *(const uint4*)(wb + (size_t)(kt2 + 4) * 16384);
      a0 = __builtin_amdgcn_mfma_f32_16x16x32_bf16(af, as_frag(h1f[0][kt2]), a0, 0, 0, 0);
      a1 = __builtin_amdgcn_mfma_f32_16x16x32_bf16(af, as_frag(h1f[1][kt2]), a1, 0, 0, 0);
    }
    // D: col=lo=edge, row=4g+i -> global col = 16cb+4g+i
    f32x4 v0, v1;
#pragma unroll
    for (int i = 0; i < 4; ++i) { v0[i] = gelu_f(a0[i]); v1[i] = gelu_f(a1[i]); }
    plog0 += v0[0]*sw[0] + v0[1]*sw[1] + v0[2]*sw[2] + v0[3]*sw[3];
    plog1 += v1[0]*sw[0] + v1[1]*sw[1] + v1[2]*sw[2] + v1[3]*sw[3];
    if (uniform) {
      f32x4 sv;
#pragma unroll
      for (int i = 0; i < 4; ++i) sv[i] = v0[i] + v1[i];
#pragma unroll
      for (int st = 1; st < 16; st <<= 1) {
#pragma unroll
        for (int i = 0; i < 4; ++i) sv[i] += __shfl_xor(sv[i], st);
      }
      if (lo == 0) {
#pragma unroll
        for (int i = 0; i < 4; ++i)
          atomicAdd(&pooledAcc[g0s * 256 + cb * 16 + g * 4 + i], sv[i]);
      }
    } else {
#pragma unroll
      for (int i = 0; i < 4; ++i) {
        atomicAdd(&pooledAcc[ga * 256 + cb * 16 + g * 4 + i], v0[i]);
        atomicAdd(&pooledAcc[gb * 256 + cb * 16 + g * 4 + i], v1[i]);
      }
    }
  }

  // ---- logits: reduce partials across g-groups, add bias + bonus ----
  plog0 += __shfl_xor(plog0, 16); plog0 += __shfl_xor(plog0, 32);
  plog1 += __shfl_xor(plog1, 16); plog1 += __shfl_xor(plog1, 32);
  if (l < 16) {
    outLogits[base + l]      = plog0 + selbr + 0.5f * fa;
    outLogits[base + 16 + l] = plog1 + selbr + 0.5f * fb_;
  }
}

// ---------------------------------------------------------------------------
__global__ __launch_bounds__(256) void stop_kernel(
    const float* __restrict__ pooledAcc, const float* __restrict__ cnts,
    const float* __restrict__ qtok,
    const float* __restrict__ ln2g, const float* __restrict__ ln2b,
    const float* __restrict__ sW1, const float* __restrict__ sb1,
    const float* __restrict__ sW2, const float* __restrict__ sb2,
    float* __restrict__ outStop, float* __restrict__ outPooled) {
  __shared__ float sIn[512], sLn[512], sRed[8];
  const int t = threadIdx.x, g = blockIdx.x;
  const int w = t >> 6, l = t & 63;
  float c = fmaxf(cnts[g], 1.0f);
  float p = pooledAcc[g * 256 + t] / c;
  outPooled[g * 256 + t] = p;
  sIn[t] = p;
  sIn[256 + t] = qtok[g * 256 + t];
  __syncthreads();
  float a = sIn[t], b = sIn[256 + t];
  float s = a + b, s2 = a * a + b * b;
#pragma unroll
  for (int m = 1; m < 64; m <<= 1) { s += __shfl_xor(s, m); s2 += __shfl_xor(s2, m); }
  if (l == 0) { sRed[w] = s; sRed[4 + w] = s2; }
  __syncthreads();
  s  = sRed[0] + sRed[1] + sRed[2] + sRed[3];
  s2 = sRed[4] + sRed[5] + sRed[6] + sRed[7];
  const float mean = s * (1.0f / 512.0f);
  const float var  = s2 * (1.0f / 512.0f) - mean * mean;
  const float rstd = rsqrtf(var + 1e-5f);
  sLn[t]       = (a - mean) * rstd * ln2g[t] + ln2b[t];
  sLn[256 + t] = (b - mean) * rstd * ln2g[256 + t] + ln2b[256 + t];
  __syncthreads();
  float accv = sb1[t];
#pragma unroll 8
  for (int k = 0; k < 512; ++k) accv += sLn[k] * sW1[k * 256 + t];
  float u = gelu_f(accv);
  float part = u * sW2[t];
#pragma unroll
  for (int m = 1; m < 64; m <<= 1) part += __shfl_xor(part, m);
  if (l == 0) sRed[w] = part;
  __syncthreads();
  if (t == 0) outStop[g] = sRed[0] + sRed[1] + sRed[2] + sRed[3] + sb2[0];
}

// ---------------------------------------------------------------------------
extern "C" void kernel_launch(void* const* d_in, const int* in_sizes, int n_in,
                              void* d_out, int out_size, void* d_ws, size_t ws_size,
                              hipStream_t stream) {
  const float* tok   = (const float*)d_in[0];
  const float* qtok  = (const float*)d_in[1];
  const int* ebatch  = (const int*)d_in[2];
  const void* smask  = d_in[3];
  const int* eheads  = (const int*)d_in[4];
  const int* etails  = (const int*)d_in[5];
  const int* curtail = (const int*)d_in[6];
  const float* ln1g  = (const float*)d_in[7];
  const float* ln1b  = (const float*)d_in[8];
  const float* W1    = (const float*)d_in[9];
  const float* b1    = (const float*)d_in[10];
  const float* W2    = (const float*)d_in[11];
  const float* b2    = (const float*)d_in[12];
  const float* selw  = (const float*)d_in[13];
  const float* selb  = (const float*)d_in[14];
  const float* ln2g  = (const float*)d_in[15];
  const float* ln2b  = (const float*)d_in[16];
  const float* sW1   = (const float*)d_in[17];
  const float* sb1   = (const float*)d_in[18];
  const float* sW2   = (const float*)d_in[19];
  const float* sb2   = (const float*)d_in[20];

  const int E = in_sizes[2];            // 400000 (divisible by 128)
  const int G = in_sizes[1] / 256;      // 64

  char* ws = (char*)d_ws;
  __bf16* W1p   = (__bf16*)(ws);                 // 131072 B
  __bf16* W2p   = (__bf16*)(ws + 131072);        // 131072 B
  float*  C0    = (float*)(ws + 262144);
  float*  GW6   = (float*)(ws + 263168);
  float*  GW7   = (float*)(ws + 264192);
  float*  pooled= (float*)(ws + 265216);         // 65536 B
  float*  cnts  = (float*)(ws + 330752);         // 256 B
  int*    mflag = (int*)(ws + 331008);           // 4 B
  (void)ws_size; (void)n_in; (void)out_size;

  hipMemsetAsync(ws + 265216, 0, 65536 + 256, stream);  // pooled + counts

  prep_pack<<<64, 256, 0, stream>>>(W1, W2, ln1g, W1p, W2p);
  prep_vec<<<1, 1024, 0, stream>>>(W1, ln1g, ln1b, b1, (const unsigned*)smask,
                                   C0, GW6, GW7, mflag);
  edge_kernel<<<E / 128, 256, 0, stream>>>(
      tok, ebatch, (const unsigned char*)smask, eheads, etails, curtail,
      W1p, W2p, C0, GW6, GW7, b2, selw, selb, mflag,
      (float*)d_out, pooled, cnts);
  stop_kernel<<<G, 256, 0, stream>>>(pooled, cnts, qtok, ln2g, ln2b,
                                     sW1, sb1, sW2, sb2,
                                     (float*)d_out + E, (float*)d_out + E + G);
}

// Round 18
// 688.489 us; speedup vs baseline: 1.0876x; 1.0876x over previous
//
#include <hip/hip_runtime.h>
#include <hip/hip_bf16.h>
#include <cstdint>

// EdgeFrontierPolicy: E=400000, G=64, H=256.
// r16 structure (277us best: cooperative 64-edge block, single-pass LN with
// fused flags, A-tile LDS swizzled, B-frags streamed from L2 reg-dbuf,
// (256,3)) made PERSISTENT: 768 blocks (3/CU) grid-stride over 6250 tiles.
// r11's persistence regression was caused by the 2-pass LN reload losing
// cache residency under drift — r16's single-pass LN removes that confound.
// Drifted co-resident blocks overlap LN(HBM) / GEMM(MFMA) / epi(VALU) phases.

typedef __bf16 bf16x8 __attribute__((ext_vector_type(8)));
typedef float  f32x4  __attribute__((ext_vector_type(4)));

__device__ __forceinline__ float gelu_f(float x) {
  float x2 = x * x;
  float t1 = __builtin_fmaf(0.1029444f, x2, 2.3022078f);
  float a  = x * t1;
  float e;
  asm("v_exp_f32 %0, %1" : "=v"(e) : "v"(a));
  float r;
  asm("v_rcp_f32 %0, %1" : "=v"(r) : "v"(e + 1.0f));
  return x - x * r;
}

__device__ __forceinline__ bf16x8 as_frag(uint4 u) {
  union { uint4 u; bf16x8 f; } c; c.u = u; return c.f;
}

// ---------------------------------------------------------------------------
// Pack W1 (ln1_g folded) / W2 into MFMA-B fragment order, bf16.
__global__ void prep_pack(const float* __restrict__ W1, const float* __restrict__ W2,
                          const float* __restrict__ ln1g,
                          __bf16* __restrict__ W1p, __bf16* __restrict__ W2p) {
  int gid = blockIdx.x * blockDim.x + threadIdx.x;   // 16384 threads
  int m  = gid >> 13;
  int b  = (gid >> 6) & 127;
  int l  = gid & 63;
  int kt = b >> 4, nt = b & 15;
  int k0 = kt * 32 + ((l >> 4) << 3);
  int n  = nt * 16 + (l & 15);
  const float* W = m ? W2 : W1;
  bf16x8 v;
#pragma unroll
  for (int i = 0; i < 8; ++i) {
    int k = k0 + i;
    float wv = W[k * 256 + n];
    if (!m) wv *= ln1g[k];
    v[i] = (__bf16)wv;
  }
  __bf16* dst = m ? W2p : W1p;
  *(bf16x8*)(dst + (size_t)(b * 64 + l) * 8) = v;
}

// C0/GW6/GW7 + mask dtype detect.
__global__ void prep_vec(const float* __restrict__ W1, const float* __restrict__ ln1g,
                         const float* __restrict__ ln1b, const float* __restrict__ b1,
                         const unsigned* __restrict__ smask_words,
                         float* __restrict__ C0, float* __restrict__ GW6,
                         float* __restrict__ GW7, int* __restrict__ maskIsByte) {
  __shared__ float red[4][256];
  const int n = threadIdx.x & 255, c = threadIdx.x >> 8;
  const int k0 = c * 64, k1 = (c == 3) ? 258 : k0 + 64;
  float s = 0.f;
#pragma unroll 4
  for (int k = k0; k < k1; ++k) s += ln1b[k] * W1[k * 256 + n];
  red[c][n] = s;
  __syncthreads();
  if (c == 0) {
    C0[n]  = b1[n] + red[0][n] + red[1][n] + red[2][n] + red[3][n];
    GW6[n] = ln1g[256] * W1[256 * 256 + n];
    GW7[n] = ln1g[257] * W1[257 * 256 + n];
  }
  if (threadIdx.x == 0) {
    int big = 0;
    for (int i = 0; i < 64; ++i) { if (smask_words[i] > 1u) big = 1; }
    *maskIsByte = big;
  }
}

// ---------------------------------------------------------------------------
#define EPB 64

// 8 K-steps; kt0 B-frags arrive preloaded in bv; depth-1 double-buffer.
__device__ __forceinline__ void gemm8_pre(const char* __restrict__ Wp,
                                          const char* aBase, unsigned swA,
                                          unsigned gA, int bOff,
                                          uint4 (&bv)[4], f32x4 (&acc)[4][4]) {
#pragma unroll
  for (int kt = 0; kt < 8; ++kt) {
    uint4 bn[4];
    if (kt < 7) {
#pragma unroll
      for (int cf = 0; cf < 4; ++cf)
        bn[cf] = *(const uint4*)(Wp + (kt + 1) * 16384 + bOff + (cf << 10));
    }
    bf16x8 av[4];
#pragma unroll
    for (int rf = 0; rf < 4; ++rf)
      av[rf] = *(const bf16x8*)(aBase + rf * 8192 + (((unsigned)(kt * 64) + gA) ^ swA));
#pragma unroll
    for (int rf = 0; rf < 4; ++rf)
#pragma unroll
      for (int cf = 0; cf < 4; ++cf)
        acc[rf][cf] = __builtin_amdgcn_mfma_f32_16x16x32_bf16(av[rf], as_frag(bv[cf]),
                                                              acc[rf][cf], 0, 0, 0);
#pragma unroll
    for (int cf = 0; cf < 4; ++cf) bv[cf] = bn[cf];
  }
}

__global__ __launch_bounds__(256, 3) void edge_kernel(
    const float* __restrict__ tok, const int* __restrict__ ebatch,
    const unsigned char* __restrict__ smaskB,
    const int* __restrict__ eheads, const int* __restrict__ etails,
    const int* __restrict__ curtail,
    const __bf16* __restrict__ W1p, const __bf16* __restrict__ W2p,
    const float* __restrict__ C0v, const float* __restrict__ GW6v,
    const float* __restrict__ GW7v, const float* __restrict__ b2v,
    const float* __restrict__ selwv, const float* __restrict__ selbv,
    const int* __restrict__ maskFlag,
    float* __restrict__ outLogits, float* __restrict__ pooledAcc,
    float* __restrict__ cnts, int nTiles) {
  __shared__ __align__(16) char As_[64 * 512];          // 32KB, XOR-swizzled rows
  __shared__ float sZa0[64], sZa1[64], sFront[64];
  __shared__ float sLog[64][4];
  __shared__ int sG[64];

  const int t = threadIdx.x;
  const int w = t >> 6, l = t & 63;
  const int bOff = (w << 12) + (l << 4);
  const int mb = *maskFlag;
  const int rA = l & 15;
  const int r0 = (l >> 4) << 2;
  const unsigned swA = (unsigned)(rA & 7) << 4;
  const unsigned gA  = (unsigned)((l >> 4) << 4);
  const char* aBase  = As_ + rA * 512;
  const int e = t >> 2, q = t & 3;

  for (int tile = blockIdx.x; tile < nTiles; tile += gridDim.x) {
    const int base = tile * EPB;
    const int ge = base + e;

    // hoist: W1-kt0 B-frags (L2) — consumed at GEMM1-kt0, drained under LN
    uint4 wb0[4];
#pragma unroll
    for (int cf = 0; cf < 4; ++cf)
      wb0[cf] = *(const uint4*)((const char*)W1p + bOff + (cf << 10));

    // ---- LN single-pass + fused flags (4 threads/edge, v[16] in regs) ----
    {
      const float* rp = tok + (size_t)ge * 256 + q * 4;
      float4 v[16];
      float s = 0.f, s2 = 0.f;
#pragma unroll
      for (int j = 0; j < 16; ++j) {
        v[j] = *(const float4*)(rp + j * 16);
        s  += v[j].x + v[j].y + v[j].z + v[j].w;
        s2 += v[j].x * v[j].x + v[j].y * v[j].y + v[j].z * v[j].z + v[j].w * v[j].w;
      }
      // flags by this edge's own q==0 lane (same wave) — overlaps the stream
      float candf = 0.f, frontf = 0.f;
      if (q == 0) {
        int g  = ebatch[ge];
        int mv = mb ? (int)smaskB[ge] : ((const int*)smaskB)[ge];
        int cand = (mv == 0);
        int cur  = curtail[g];
        int fr   = cand && ((eheads[ge] == cur) || (etails[ge] == cur));
        candf = (float)cand; frontf = (float)fr;
        sFront[e] = (float)fr; sG[e] = g;
      }
      const float a0 = __shfl(candf,  l & 60);   // from q==0 lane of this edge
      const float a1 = __shfl(frontf, l & 60);
      s  += __shfl_xor(s, 1);  s  += __shfl_xor(s, 2);
      s2 += __shfl_xor(s2, 1); s2 += __shfl_xor(s2, 2);
      s += a0 + a1; s2 += a0 + a1;               // 0/1 flags: x == x^2
      const float mean = s * (1.0f / 258.0f);
      const float var  = s2 * (1.0f / 258.0f) - mean * mean;
      const float rstd = rsqrtf(var + 1e-5f);
      const float nm   = -mean * rstd;
      const unsigned sw = (unsigned)(e & 7) << 4;
#pragma unroll
      for (int j = 0; j < 16; ++j) {
        union { __bf16 h[4]; uint2 u; } cv;
        cv.h[0] = (__bf16)__builtin_fmaf(v[j].x, rstd, nm);
        cv.h[1] = (__bf16)__builtin_fmaf(v[j].y, rstd, nm);
        cv.h[2] = (__bf16)__builtin_fmaf(v[j].z, rstd, nm);
        cv.h[3] = (__bf16)__builtin_fmaf(v[j].w, rstd, nm);
        unsigned off = (unsigned)(q * 8 + j * 32);
        *(uint2*)(As_ + e * 512 + (off ^ sw)) = cv.u;
      }
      if (q == 0) {
        sZa0[e] = __builtin_fmaf(a0, rstd, nm);
        sZa1[e] = __builtin_fmaf(a1, rstd, nm);
      }
    }
    __syncthreads();   // barrier 1: A tile + za + sG visible

    if (t == 0) {  // counts: run-length over sorted graph ids (overlaps G1)
      int cg = sG[0]; float run = 1.f;
      for (int ee = 1; ee < EPB; ++ee) {
        int g = sG[ee];
        if (g == cg) run += 1.f;
        else { atomicAdd(&cnts[cg], run); cg = g; run = 1.f; }
      }
      atomicAdd(&cnts[cg], run);
    }

    // ---- per-thread acc init (C0 + rank-2 aux) ----
    f32x4 acc[4][4];
    {
      float c0r[4], w6r[4], w7r[4];
#pragma unroll
      for (int cf = 0; cf < 4; ++cf) {
        int col = w * 64 + cf * 16 + rA;
        c0r[cf] = C0v[col]; w6r[cf] = GW6v[col]; w7r[cf] = GW7v[col];
      }
      f32x4 za0q[4], za1q[4];
#pragma unroll
      for (int rf = 0; rf < 4; ++rf) {
        za0q[rf] = *(const f32x4*)&sZa0[rf * 16 + r0];
        za1q[rf] = *(const f32x4*)&sZa1[rf * 16 + r0];
      }
#pragma unroll
      for (int rf = 0; rf < 4; ++rf)
#pragma unroll
        for (int cf = 0; cf < 4; ++cf)
#pragma unroll
          for (int i = 0; i < 4; ++i)
            acc[rf][cf][i] = c0r[cf] + za0q[rf][i] * w6r[cf] + za1q[rf][i] * w7r[cf];
    }

    // ---- GEMM1 (B from L2, kt0 preloaded, no barriers) ----
    gemm8_pre((const char*)W1p, aBase, swA, gA, bOff, wb0, acc);
    __syncthreads();   // barrier 2: all GEMM1 A-reads complete

    // hoist: W2-kt0 B-frags — L2 latency hides under epilogue-1's gelu
#pragma unroll
    for (int cf = 0; cf < 4; ++cf)
      wb0[cf] = *(const uint4*)((const char*)W2p + bOff + (cf << 10));

    // ---- epilogue 1: gelu -> bf16 back into A tile ----
#pragma unroll
    for (int rf = 0; rf < 4; ++rf)
#pragma unroll
      for (int i = 0; i < 4; ++i) {
        int row = rf * 16 + r0 + i;
        char* rowp = As_ + row * 512;
        unsigned sw = (unsigned)(row & 7) << 4;
#pragma unroll
        for (int cf = 0; cf < 4; ++cf) {
          int col = w * 64 + cf * 16 + rA;
          *(__bf16*)(rowp + (((unsigned)(col * 2)) ^ sw)) = (__bf16)gelu_f(acc[rf][cf][i]);
        }
      }
    __syncthreads();   // barrier 3: h1 visible

    // ---- GEMM2 ----
#pragma unroll
    for (int cf = 0; cf < 4; ++cf) {
      float bb = b2v[w * 64 + cf * 16 + rA];
#pragma unroll
      for (int rf = 0; rf < 4; ++rf)
#pragma unroll
        for (int i = 0; i < 4; ++i) acc[rf][cf][i] = bb;
    }
    gemm8_pre((const char*)W2p, aBase, swA, gA, bOff, wb0, acc);

    // ---- epilogue 2: gelu -> logits + pooled ----
#pragma unroll
    for (int rf = 0; rf < 4; ++rf)
#pragma unroll
      for (int cf = 0; cf < 4; ++cf)
#pragma unroll
        for (int i = 0; i < 4; ++i) acc[rf][cf][i] = gelu_f(acc[rf][cf][i]);

    {
      float lwr[4];
#pragma unroll
      for (int cf = 0; cf < 4; ++cf) lwr[cf] = selwv[w * 64 + cf * 16 + rA];
#pragma unroll
      for (int rf = 0; rf < 4; ++rf)
#pragma unroll
        for (int i = 0; i < 4; ++i) {
          float p = acc[rf][0][i] * lwr[0] + acc[rf][1][i] * lwr[1]
                  + acc[rf][2][i] * lwr[2] + acc[rf][3][i] * lwr[3];
          p += __shfl_xor(p, 1); p += __shfl_xor(p, 2);
          p += __shfl_xor(p, 4); p += __shfl_xor(p, 8);
          if (rA == 0) sLog[rf * 16 + r0 + i][w] = p;
        }
    }
    __syncthreads();   // barrier 4: sLog complete
    if (t < 64)
      outLogits[base + t] = sLog[t][0] + sLog[t][1] + sLog[t][2] + sLog[t][3]
                          + selbv[0] + 0.5f * sFront[t];

    if (sG[0] == sG[EPB - 1]) {
      int g = sG[0];
#pragma unroll
      for (int cf = 0; cf < 4; ++cf) {
        float sv = 0.f;
#pragma unroll
        for (int rf = 0; rf < 4; ++rf)
#pragma unroll
          for (int i = 0; i < 4; ++i) sv += acc[rf][cf][i];
        sv += __shfl_xor(sv, 16);
        sv += __shfl_xor(sv, 32);
        if (l < 16) atomicAdd(&pooledAcc[g * 256 + w * 64 + cf * 16 + l], sv);
      }
    } else {  // graph-boundary block (rare)
#pragma unroll
      for (int rf = 0; rf < 4; ++rf)
#pragma unroll
        for (int i = 0; i < 4; ++i) {
          int row = rf * 16 + r0 + i;
          int g = sG[row];
#pragma unroll
          for (int cf = 0; cf < 4; ++cf)
            atomicAdd(&pooledAcc[g * 256 + w * 64 + cf * 16 + rA], acc[rf][cf][i]);
        }
    }
    __syncthreads();   // barrier 5: protect sG/sFront/sZa/As_ for next tile
  }
}

// ---------------------------------------------------------------------------
__global__ __launch_bounds__(256) void stop_kernel(
    const float* __restrict__ pooledAcc, const float* __restrict__ cnts,
    const float* __restrict__ qtok,
    const float* __restrict__ ln2g, const float* __restrict__ ln2b,
    const float* __restrict__ sW1, const float* __restrict__ sb1,
    const float* __restrict__ sW2, const float* __restrict__ sb2,
    float* __restrict__ outStop, float* __restrict__ outPooled) {
  __shared__ float sIn[512], sLn[512], sRed[8];
  const int t = threadIdx.x, g = blockIdx.x;
  const int w = t >> 6, l = t & 63;
  float c = fmaxf(cnts[g], 1.0f);
  float p = pooledAcc[g * 256 + t] / c;
  outPooled[g * 256 + t] = p;
  sIn[t] = p;
  sIn[256 + t] = qtok[g * 256 + t];
  __syncthreads();
  float a = sIn[t], b = sIn[256 + t];
  float s = a + b, s2 = a * a + b * b;
#pragma unroll
  for (int m = 1; m < 64; m <<= 1) { s += __shfl_xor(s, m); s2 += __shfl_xor(s2, m); }
  if (l == 0) { sRed[w] = s; sRed[4 + w] = s2; }
  __syncthreads();
  s  = sRed[0] + sRed[1] + sRed[2] + sRed[3];
  s2 = sRed[4] + sRed[5] + sRed[6] + sRed[7];
  const float mean = s * (1.0f / 512.0f);
  const float var  = s2 * (1.0f / 512.0f) - mean * mean;
  const float rstd = rsqrtf(var + 1e-5f);
  sLn[t]       = (a - mean) * rstd * ln2g[t] + ln2b[t];
  sLn[256 + t] = (b - mean) * rstd * ln2g[256 + t] + ln2b[256 + t];
  __syncthreads();
  float accv = sb1[t];
#pragma unroll 8
  for (int k = 0; k < 512; ++k) accv += sLn[k] * sW1[k * 256 + t];
  float u = gelu_f(accv);
  float part = u * sW2[t];
#pragma unroll
  for (int m = 1; m < 64; m <<= 1) part += __shfl_xor(part, m);
  if (l == 0) sRed[w] = part;
  __syncthreads();
  if (t == 0) outStop[g] = sRed[0] + sRed[1] + sRed[2] + sRed[3] + sb2[0];
}

// ---------------------------------------------------------------------------
extern "C" void kernel_launch(void* const* d_in, const int* in_sizes, int n_in,
                              void* d_out, int out_size, void* d_ws, size_t ws_size,
                              hipStream_t stream) {
  const float* tok   = (const float*)d_in[0];
  const float* qtok  = (const float*)d_in[1];
  const int* ebatch  = (const int*)d_in[2];
  const void* smask  = d_in[3];
  const int* eheads  = (const int*)d_in[4];
  const int* etails  = (const int*)d_in[5];
  const int* curtail = (const int*)d_in[6];
  const float* ln1g  = (const float*)d_in[7];
  const float* ln1b  = (const float*)d_in[8];
  const float* W1    = (const float*)d_in[9];
  const float* b1    = (const float*)d_in[10];
  const float* W2    = (const float*)d_in[11];
  const float* b2    = (const float*)d_in[12];
  const float* selw  = (const float*)d_in[13];
  const float* selb  = (const float*)d_in[14];
  const float* ln2g  = (const float*)d_in[15];
  const float* ln2b  = (const float*)d_in[16];
  const float* sW1   = (const float*)d_in[17];
  const float* sb1   = (const float*)d_in[18];
  const float* sW2   = (const float*)d_in[19];
  const float* sb2   = (const float*)d_in[20];

  const int E = in_sizes[2];            // 400000
  const int G = in_sizes[1] / 256;      // 64

  char* ws = (char*)d_ws;
  __bf16* W1p   = (__bf16*)(ws);                 // 131072 B
  __bf16* W2p   = (__bf16*)(ws + 131072);        // 131072 B
  float*  C0    = (float*)(ws + 262144);
  float*  GW6   = (float*)(ws + 263168);
  float*  GW7   = (float*)(ws + 264192);
  float*  pooled= (float*)(ws + 265216);         // 65536 B
  float*  cnts  = (float*)(ws + 330752);         // 256 B
  int*    mflag = (int*)(ws + 331008);           // 4 B
  (void)ws_size; (void)n_in; (void)out_size;

  hipMemsetAsync(ws + 265216, 0, 65536 + 256, stream);  // pooled + counts

  prep_pack<<<64, 256, 0, stream>>>(W1, W2, ln1g, W1p, W2p);
  prep_vec<<<1, 1024, 0, stream>>>(W1, ln1g, ln1b, b1, (const unsigned*)smask,
                                   C0, GW6, GW7, mflag);
  edge_kernel<<<768, 256, 0, stream>>>(
      tok, ebatch, (const unsigned char*)smask, eheads, etails, curtail,
      W1p, W2p, C0, GW6, GW7, b2, selw, selb, mflag,
      (float*)d_out, pooled, cnts, E / EPB);
  stop_kernel<<<G, 256, 0, stream>>>(pooled, cnts, qtok, ln2g, ln2b,
                                     sW1, sb1, sW2, sb2,
                                     (float*)d_out + E, (float*)d_out + E + G);
}